// Round 3
// baseline (2320.041 us; speedup 1.0000x reference)
//
#include <hip/hip_runtime.h>
#include <stdint.h>
#include <limits.h>

// ---------------------------------------------------------------------------
// RPN loss, bit-exact replication of the JAX reference (incl. threefry PRNG).
// Round 11: single ORDINARY kernel (graph-capturable, unlike r10's
// hipLaunchCooperativeKernel which silently failed under stream capture ->
// all-zero output). Grid-wide sync via software barrier: device-scope atomic
// counter + __threadfence() release/acquire on both sides (handles per-XCD
// L2 non-coherence explicitly). 3 barriers instead of 6 dispatch boundaries:
//   phase1 iou/labels (all blocks, r9 body verbatim)      -> gbar
//   phase2 force + cutoff (block 0 only, fenced locally)  -> gbar
//   phase3 cand+loss merged (all blocks; cutoff-bucket
//          anchors only append, sure-kept sum loss now)   -> gbar
//   phase4 candidate ranking + their losses + final (block 0)
// Co-residency arithmetic: 256 thr = 4 waves, 8KB LDS, ~32 VGPR ->
// 8 blocks/CU capacity = 2048 >= 1152 grid. Bounded spin bailout so a
// placement failure fails fast instead of hanging the harness.
// ---------------------------------------------------------------------------
#define PARTITIONABLE 1

#define B_ 8
#define K_ 9
#define H_ 64
#define W_ 64
#define G_ 128
#define A_ 36864            // K*H*W
#define HALF_A 18432
#define NBUCK 8192          // buckets over 23-bit v (v>>10)
#define CAP 1024            // cutoff-bucket candidate capacity (expected ~5)
#define NLAB  1152          // (A_/256) * B_  -- one block per 256 anchors

struct KeyParams { uint32_t k[B_][4]; };   // per image: k1.(0,1), k2.(0,1)

__host__ __device__ static inline uint32_t rotl32(uint32_t x, int r) {
  return (x << r) | (x >> (32 - r));
}

// JAX threefry2x32: 20 rounds, key injections every 4 rounds.
__host__ __device__ static inline void tf2x32(uint32_t k0, uint32_t k1,
                                              uint32_t x0, uint32_t x1,
                                              uint32_t& o0, uint32_t& o1) {
  uint32_t ks2 = k0 ^ k1 ^ 0x1BD11BDAu;
  x0 += k0; x1 += k1;
#define TF_R(r) { x0 += x1; x1 = rotl32(x1, r); x1 ^= x0; }
  TF_R(13) TF_R(15) TF_R(26) TF_R(6)
  x0 += k1;  x1 += ks2 + 1u;
  TF_R(17) TF_R(29) TF_R(16) TF_R(24)
  x0 += ks2; x1 += k0 + 2u;
  TF_R(13) TF_R(15) TF_R(26) TF_R(6)
  x0 += k0;  x1 += k1 + 3u;
  TF_R(17) TF_R(29) TF_R(16) TF_R(24)
  x0 += k1;  x1 += ks2 + 4u;
  TF_R(13) TF_R(15) TF_R(26) TF_R(6)
  x0 += ks2; x1 += k0 + 5u;
#undef TF_R
  o0 = x0; o1 = x1;
}

// 23-bit sort key of jax.random.uniform(key,(A,))[a]; score monotone in v,
// score ties <=> equal v (stable argsort -> smaller index ranks first).
__device__ static inline uint32_t anchor_vbits(uint32_t k0, uint32_t k1, int a) {
  uint32_t o0, o1;
#if PARTITIONABLE
  tf2x32(k0, k1, 0u, (uint32_t)a, o0, o1);
  return (o0 ^ o1) >> 9;
#else
  if (a < HALF_A) { tf2x32(k0, k1, (uint32_t)a, (uint32_t)(a + HALF_A), o0, o1); return o0 >> 9; }
  else            { tf2x32(k0, k1, (uint32_t)(a - HALF_A), (uint32_t)a, o0, o1); return o1 >> 9; }
#endif
}

// Box area, contraction off (bit-identical to XLA's plain fp32 ops).
__device__ static inline float area_of(float x0, float y0, float x1, float y1) {
#pragma clang fp contract(off)
  return (x1 - x0) * (y1 - y0);
}

// IoU with anchor area hoisted (bit-identical product order, XLA op-by-op).
__device__ static inline float iou_pre_a(float a0, float a1, float a2, float a3,
                                         float area_a,
                                         float g0, float g1, float g2, float g3) {
#pragma clang fp contract(off)
  float ltx = fmaxf(a0, g0), lty = fmaxf(a1, g1);
  float rbx = fminf(a2, g2), rby = fminf(a3, g3);
  float w = rbx - ltx; w = (w < 0.f) ? 0.f : w;
  float h = rby - lty; h = (h < 0.f) ? 0.f : h;
  float inter  = w * h;
  float area_g = (g2 - g0) * (g3 - g1);
  return inter / (area_a + area_g - inter + 1e-6f);
}

__device__ static inline void encode4(float4 an, float4 gg, float* tt) {
#pragma clang fp contract(off)
  float aw  = an.z - an.x,            ah  = an.w - an.y;
  float acx = (an.x + an.z) * 0.5f,   acy = (an.y + an.w) * 0.5f;
  float gw  = gg.z - gg.x,            gh  = gg.w - gg.y;
  float gcx = (gg.x + gg.z) * 0.5f,   gcy = (gg.y + gg.w) * 0.5f;
  tt[0] = (gcx - acx) / aw;
  tt[1] = (gcy - acy) / ah;
  tt[2] = logf(gw / aw);
  tt[3] = logf(gh / ah);
}

__device__ static inline int block_reduce_int(int v, int* sh) {
  int t = threadIdx.x;
  sh[t] = v; __syncthreads();
  for (int s = 128; s > 0; s >>= 1) { if (t < s) sh[t] += sh[t + s]; __syncthreads(); }
  int r = sh[0]; __syncthreads();
  return r;
}
__device__ static inline float block_reduce_float(float v, float* sh) {
  int t = threadIdx.x;
  sh[t] = v; __syncthreads();
  for (int s = 128; s > 0; s >>= 1) { if (t < s) sh[t] += sh[t + s]; __syncthreads(); }
  float r = sh[0]; __syncthreads();
  return r;
}

// Software grid barrier. Release fence -> arrive -> acquire-spin -> acquire
// fence. __threadfence() on gfx9xx agent scope emits the L2 writeback /
// invalidate needed for cross-XCD visibility of the plain stores.
// Bounded spin: on placement failure we break (wrong answer, no hang).
__device__ static inline void gbar(int* bar, int nblk) {
  __syncthreads();                      // all lanes' stores drained (vmcnt 0)
  if (threadIdx.x == 0) {
    __threadfence();                    // release
    __hip_atomic_fetch_add(bar, 1, __ATOMIC_RELEASE, __HIP_MEMORY_SCOPE_AGENT);
    int guard = 0;
    while (__hip_atomic_load(bar, __ATOMIC_ACQUIRE, __HIP_MEMORY_SCOPE_AGENT) < nblk) {
      __builtin_amdgcn_s_sleep(8);
      if (++guard > (1 << 22)) break;   // ~fail fast, never hang harness
    }
    __threadfence();                    // acquire
  }
  __syncthreads();
}

// ---------------------------------------------------------------------------
// The single kernel. Grid = NLAB x 256, ordinary launch (graph-capturable).
// ---------------------------------------------------------------------------
__global__ __launch_bounds__(256) void mega_k(
    const float* __restrict__ anchors, const float* __restrict__ gtb,
    const float* __restrict__ cls, const float* __restrict__ boxp,
    int* __restrict__ labels, int* __restrict__ mgt,
    uint32_t* __restrict__ vpos, uint32_t* __restrict__ vneg,
    int* __restrict__ ghist, int* __restrict__ counts,
    unsigned long long* __restrict__ gmax,
    int* __restrict__ cbR, int* __restrict__ targets,
    int* __restrict__ ccnt, uint32_t* __restrict__ cvv, int* __restrict__ cii,
    float* __restrict__ bsums, int* __restrict__ bars,
    float* __restrict__ out, KeyParams kp) {
  __shared__ float2 gp01[2 * G_];               // (x0,y0), duplicated for mod-free idx
  __shared__ float2 gp23[2 * G_];               // (x1,y1), duplicated
  __shared__ unsigned long long slot2[2 * G_];  // per-(block,g residue) best pack
  __shared__ int red[256];                      // int reduce / cutoff seg sums
  __shared__ float redf[256];

  const int bid = blockIdx.x;
  const int t = threadIdx.x;
  const int b  = bid / (A_ / 256);
  const int xb = bid % (A_ / 256);
  const int a  = xb * 256 + t;                   // < A_ exactly
  const size_t idx = (size_t)b * A_ + a;

  // ========== phase 1: IoU + labels + PRNG + hist + counts (r9 body) ======
  {
    if (t < G_) {
      float4 gg = ((const float4*)gtb)[b * G_ + t];
      float2 p01; p01.x = gg.x; p01.y = gg.y;
      float2 p23; p23.x = gg.z; p23.y = gg.w;
      gp01[t] = p01; gp01[t + G_] = p01;
      gp23[t] = p23; gp23[t + G_] = p23;
    }
    slot2[t] = 0ull;                             // covers all 256 residues
    __syncthreads();

    float4 an = ((const float4*)anchors)[a];
    float area_a = area_of(an.x, an.y, an.z, an.w);
    const int t7 = t & (G_ - 1);
    const unsigned long long alow = (unsigned long long)(~(uint32_t)a);
    unsigned long long blp = 0ull;               // (iou_bits<<32 | g^127) running max
#pragma unroll 4
    for (int s = 0; s < G_; s++) {
      const int gi = t7 + s;                     // in [0, 254]; g = gi & 127
      float2 p01 = gp01[gi];
      float2 p23 = gp23[gi];
      float v = iou_pre_a(an.x, an.y, an.z, an.w, area_a,
                          p01.x, p01.y, p23.x, p23.y);
      unsigned long long hi = (unsigned long long)__float_as_uint(v) << 32;
      unsigned long long lp = hi | (unsigned)((gi & (G_ - 1)) ^ (G_ - 1));
      if (lp > blp) blp = lp;                    // (higher iou, then smaller g)
      atomicMax(&slot2[gi], hi | alow);          // fire-and-forget, lanes distinct
    }
    __syncthreads();
    if (t < G_) {
      unsigned long long p = slot2[t];
      unsigned long long q = slot2[t + G_];
      if (q > p) p = q;
      atomicMax(&gmax[b * G_ + t], p);           // once per (block, g)
    }

    float bv = __uint_as_float((uint32_t)(blp >> 32));
    int   bi = ((int)(blp & (unsigned long long)(G_ - 1))) ^ (G_ - 1);
    int lb = (bv < 0.3f) ? 0 : ((bv >= 0.7f) ? 1 : -1);
    uint32_t vp = anchor_vbits(kp.k[b][0], kp.k[b][1], a);
    uint32_t vn = anchor_vbits(kp.k[b][2], kp.k[b][3], a);
    labels[idx] = lb;
    mgt[idx]    = bi;
    vpos[idx]   = vp;
    vneg[idx]   = vn;
    if (lb == 1)      atomicAdd(&ghist[(b * 2 + 0) * NBUCK + (vp >> 10)], 1);
    else if (lb == 0) atomicAdd(&ghist[(b * 2 + 1) * NBUCK + (vn >> 10)], 1);
    // packed counts: pos | neg<<16 (block sums <= 256, safe)
    int packed = (lb == 1 ? 1 : 0) | ((lb == 0 ? 1 : 0) << 16);
    int rr = block_reduce_int(packed, red);
    if (t == 0) {
      atomicAdd(&counts[b * 2 + 0], rr & 0xFFFF);
      atomicAdd(&counts[b * 2 + 1], rr >> 16);
    }
  }
  gbar(&bars[0], NLAB);

  // ========== phase 2: force + cutoff (block 0 only) ======================
  if (bid == 0) {
    // --- force best anchor per gt (1024 items, 4 iterations) ---
    for (int it = 0; it < (B_ * G_) / 256; ++it) {
      int tg = it * 256 + t;
      int fb = tg / G_;
      int fa = (int)(~(uint32_t)(gmax[tg] & 0xFFFFFFFFull));
      size_t fidx = (size_t)fb * A_ + fa;
      int old = atomicExch(&labels[fidx], 1);
      if (old != 1) {
        atomicAdd(&counts[fb * 2 + 0], 1);
        atomicAdd(&ghist[(fb * 2 + 0) * NBUCK + (vpos[fidx] >> 10)], 1);
        if (old == 0) {
          atomicSub(&counts[fb * 2 + 1], 1);
          atomicSub(&ghist[(fb * 2 + 1) * NBUCK + (vneg[fidx] >> 10)], 1);
        }
      }
    }
    __threadfence();                   // make our atomics visible to our plain loads
    __syncthreads();

    // --- cutoff bucket + remainder, 16 rows serial ---
    for (int row = 0; row < 2 * B_; ++row) {
      const int rb = row >> 1, rc = row & 1;
      int npos = counts[rb * 2 + 0], nneg = counts[rb * 2 + 1];
      int tp = npos < 128 ? npos : 128;
      int tn = 256 - tp; if (nneg < tn) tn = nneg;
      const int target = (rc == 0) ? tp : tn;
      const int* hist = ghist + (size_t)row * NBUCK;
      { int s = 0; const int base = t * 32;
        for (int i = 0; i < 32; i++) s += hist[base + i];
        red[t] = s; }
      __syncthreads();
      if (t == 0) {
        int cb = INT_MAX, R = 0;
        if (target > 0) {
          int cum = 0, si = -1;
          for (int i = 255; i >= 0; i--) { if (cum + red[i] >= target) { si = i; break; } cum += red[i]; }
          for (int j = si * 32 + 31; j >= si * 32; j--) {
            if (cum + hist[j] >= target) { cb = j; R = target - cum; break; }
            cum += hist[j];
          }
        }
        cbR[row * 2 + 0] = cb;
        cbR[row * 2 + 1] = R;
        targets[row] = target;
      }
      __syncthreads();
    }
  }
  gbar(&bars[1], NLAB);

  // ========== phase 3: cand + loss merged (all blocks) ====================
  {
    float sb = 0.f, ss = 0.f;
    int lb = labels[idx];
    if (lb >= 0) {
      int c = (lb == 1) ? 0 : 1;
      int row = b * 2 + c;
      uint32_t v = (c == 0 ? vpos : vneg)[idx];
      int bucket = (int)(v >> 10);
      int cb = cbR[row * 2];
      if (bucket == cb) {
        // deferred: rank unknown until all candidates appended
        int p = atomicAdd(&ccnt[row], 1);
        if (p < CAP) { cvv[row * CAP + p] = v; cii[row * CAP + p] = a; }
      } else if (bucket > cb) {                  // sure-kept (cb==INT_MAX -> never)
        int kk = a % K_; int hw = a / K_; int hh = hw / W_; int wx = hw % W_;
        float x  = cls[(((size_t)b * K_ + kk) * H_ + hh) * W_ + wx];
        float sp = fmaxf(x, 0.f) + log1pf(expf(-fabsf(x)));   // logaddexp(x,0)
        sb = (lb == 1) ? (sp - x) : sp;
        if (lb == 1) {
          float4 an = ((const float4*)anchors)[a];
          int    mg = mgt[idx];
          float4 gg = ((const float4*)gtb)[b * G_ + mg];
          float tt[4]; encode4(an, gg, tt);
          for (int cc2 = 0; cc2 < 4; cc2++) {
            float p = boxp[(((size_t)b * (4 * K_) + (4 * kk + cc2)) * H_ + hh) * W_ + wx];
            float d = p - tt[cc2];
            float ad = fabsf(d);
            ss += (ad < 1.f) ? (0.5f * d * d) : (ad - 0.5f);
          }
        }
      }
    }
    float sbT = block_reduce_float(sb, redf);
    float ssT = block_reduce_float(ss, redf);
    if (t == 0) {
      if (sbT != 0.f) atomicAdd(&bsums[b * 2 + 0], sbT);
      if (ssT != 0.f) atomicAdd(&bsums[b * 2 + 1], ssT);
    }
  }
  gbar(&bars[2], NLAB);
  if (bid != 0) return;

  // ========== phase 4: candidate ranking + losses + final (block 0) =======
  for (int row = 0; row < 2 * B_; ++row) {
    int c2 = ccnt[row]; if (c2 > CAP) c2 = CAP;
    int R = cbR[row * 2 + 1];
    const int rb = row >> 1;
    const bool pos = ((row & 1) == 0);
    float sbl = 0.f, ssl = 0.f;
    for (int j = t; j < c2; j += 256) {
      uint32_t v = cvv[row * CAP + j]; int a2 = cii[row * CAP + j];
      int r = 0;
      for (int k2 = 0; k2 < c2; k2++) {
        uint32_t vk = cvv[row * CAP + k2]; int ik = cii[row * CAP + k2];
        if (vk > v || (vk == v && ik < a2)) r++;
      }
      if (r < R) {                                // kept: stable-rank subsample
        int kk = a2 % K_; int hw = a2 / K_; int hh = hw / W_; int wx = hw % W_;
        float x = cls[(((size_t)rb * K_ + kk) * H_ + hh) * W_ + wx];
        float sp = fmaxf(x, 0.f) + log1pf(expf(-fabsf(x)));
        sbl += pos ? (sp - x) : sp;
        if (pos) {
          float4 an = ((const float4*)anchors)[a2];
          int mg = mgt[(size_t)rb * A_ + a2];
          float4 gg = ((const float4*)gtb)[rb * G_ + mg];
          float tt[4]; encode4(an, gg, tt);
          for (int cc2 = 0; cc2 < 4; cc2++) {
            float p = boxp[(((size_t)rb * (4 * K_) + (4 * kk + cc2)) * H_ + hh) * W_ + wx];
            float d = p - tt[cc2];
            float ad = fabsf(d);
            ssl += (ad < 1.f) ? (0.5f * d * d) : (ad - 0.5f);
          }
        }
      }
    }
    if (sbl != 0.f) atomicAdd(&bsums[rb * 2 + 0], sbl);
    if (ssl != 0.f) atomicAdd(&bsums[rb * 2 + 1], ssl);
  }
  __threadfence();
  __syncthreads();
  if (t == 0) {
    float cl = 0.f, bl = 0.f;
    for (int bb = 0; bb < B_; bb++) {
      int tp = targets[bb * 2 + 0], tn = targets[bb * 2 + 1];
      cl += bsums[bb * 2 + 0] / fmaxf((float)(tp + tn), 1.f);
      bl += bsums[bb * 2 + 1] / fmaxf(4.f * (float)tp, 1.f);
    }
    cl *= 0.125f; bl *= 0.125f;
    out[0] = cl; out[1] = bl; out[2] = cl + bl;
  }
}

static void compute_keys(KeyParams& kp) {
  const uint32_t r0 = 0u, r1 = 42u;        // jax.random.key(42) -> (hi, lo)
#if PARTITIONABLE
  for (int b = 0; b < B_; b++) {
    uint32_t kb0, kb1;
    tf2x32(r0, r1, 0u, (uint32_t)b, kb0, kb1);        // split(root, 8)[b]
    uint32_t a0, a1, c0, c1;
    tf2x32(kb0, kb1, 0u, 0u, a0, a1);                 // split(key)[0] = k1
    tf2x32(kb0, kb1, 0u, 1u, c0, c1);                 // split(key)[1] = k2
    kp.k[b][0] = a0; kp.k[b][1] = a1; kp.k[b][2] = c0; kp.k[b][3] = c1;
  }
#else
  uint32_t o0[8], o1[8], flat[16];
  for (int i = 0; i < 8; i++) tf2x32(r0, r1, (uint32_t)i, (uint32_t)(8 + i), o0[i], o1[i]);
  for (int i = 0; i < 8; i++) { flat[i] = o0[i]; flat[8 + i] = o1[i]; }
  for (int b = 0; b < B_; b++) {
    uint32_t kb0 = flat[2 * b], kb1 = flat[2 * b + 1];
    uint32_t a0, b0, a1, b1;
    tf2x32(kb0, kb1, 0u, 2u, a0, b0);
    tf2x32(kb0, kb1, 1u, 3u, a1, b1);
    kp.k[b][0] = a0; kp.k[b][1] = a1; kp.k[b][2] = b0; kp.k[b][3] = b1;
  }
#endif
}

extern "C" void kernel_launch(void* const* d_in, const int* in_sizes, int n_in,
                              void* d_out, int out_size, void* d_ws, size_t ws_size,
                              hipStream_t stream) {
  const float* cls     = (const float*)d_in[0];   // [B,K,H,W]
  const float* boxp    = (const float*)d_in[1];   // [B,4K,H,W]
  const float* anchors = (const float*)d_in[2];   // [A,4]
  const float* gtb     = (const float*)d_in[3];   // [B,G,4]
  float* out = (float*)d_out;

  uint8_t* w = (uint8_t*)d_ws;
  // zeroed region [0, 532736): gmax + ghist + counts + ccnt + bsums + bars
  unsigned long long* gmax = (unsigned long long*)w;    // B*G u64 (8 KB)
  int*      ghist   = (int*)(w + 8192);                 // 16*NBUCK ints (512 KB)
  int*      counts  = (int*)(w + 532480);               // 16
  int*      ccnt    = counts + 16;                      // 16
  float*    bsums   = (float*)(ccnt + 16);              // 16
  int*      bars    = (int*)(bsums + 16);               // 4 barrier counters
  // non-zeroed region
  int*      labels  = (int*)(w + 532736);               // B*A
  int*      mgt     = labels + (size_t)B_ * A_;         // B*A
  uint32_t* vpos    = (uint32_t*)(mgt + (size_t)B_ * A_);  // B*A
  uint32_t* vneg    = vpos + (size_t)B_ * A_;           // B*A
  int*      cbR     = (int*)(vneg + (size_t)B_ * A_);   // 32
  int*      targets = cbR + 32;                         // 16
  uint32_t* cvv     = (uint32_t*)(targets + 16);        // 16*CAP
  int*      cii     = (int*)(cvv + 16 * CAP);           // 16*CAP

  KeyParams kp;
  compute_keys(kp);

  (void)hipMemsetAsync(w, 0, 532736, stream);
  mega_k<<<NLAB, 256, 0, stream>>>(anchors, gtb, cls, boxp, labels, mgt,
                                   vpos, vneg, ghist, counts, gmax,
                                   cbR, targets, ccnt, cvv, cii,
                                   bsums, bars, out, kp);
}

// Round 5
// 216.439 us; speedup vs baseline: 10.7192x; 10.7192x over previous
//
#include <hip/hip_runtime.h>
#include <stdint.h>
#include <limits.h>

// ---------------------------------------------------------------------------
// RPN loss, bit-exact replication of the JAX reference (incl. threefry PRNG).
// Round 13 == Round 12 resubmitted verbatim (r12 got "container failed twice"
// -- an infra error with no test verdict; kernel audit found no hang/OOB
// mechanism, so the experiment is rerun unchanged).
//
// Design: fence-free fusion via last-block ticket. r11's spin barrier was
// correct (absmax 0.0) but each acquire-poll emitted an L2 invalidate ->
// 2.3ms of cache-op storm (VALUBusy 1.6%). New mechanism, NO fences at all:
//  - cross-block-read data is stored with RELAXED AGENT atomic stores (sc1,
//    bypass L2, lands at LLC; the coherence point) -- plain store speed.
//  - each block: __syncthreads() (drains vmcnt -> stores acked at LLC), then
//    one RELAXED agent atomicAdd(ticket). The block drawing NLAB-1 is the
//    last to FINISH; it alone runs the serial tail. No polling, no wbl2/inv.
//  - K1 = r9 IoU/label body (proven) + tail{force + cutoff}.
//    K2 = merged cand+loss (r11 phase3, proven) + tail{rank + final}.
//    K1->K2 plain-store visibility via the ordinary dispatch boundary.
//  - NBUCK 8192->1024 (v>>13): kept-set identical (exact rank within cutoff
//    bucket); memset 532KB->74KB; cutoff scan is a 3-level suffix scan.
// ---------------------------------------------------------------------------
#define PARTITIONABLE 1

#define B_ 8
#define K_ 9
#define H_ 64
#define W_ 64
#define G_ 128
#define A_ 36864            // K*H*W
#define HALF_A 18432
#define NBUCK 1024          // buckets over 23-bit v (v>>13)
#define BSHIFT 13
#define CAP 1024            // cutoff-bucket candidate capacity (expected ~40)
#define NLAB  1152          // (A_/256) * B_  -- one block per 256 anchors

struct KeyParams { uint32_t k[B_][4]; };   // per image: k1.(0,1), k2.(0,1)

__host__ __device__ static inline uint32_t rotl32(uint32_t x, int r) {
  return (x << r) | (x >> (32 - r));
}

// JAX threefry2x32: 20 rounds, key injections every 4 rounds.
__host__ __device__ static inline void tf2x32(uint32_t k0, uint32_t k1,
                                              uint32_t x0, uint32_t x1,
                                              uint32_t& o0, uint32_t& o1) {
  uint32_t ks2 = k0 ^ k1 ^ 0x1BD11BDAu;
  x0 += k0; x1 += k1;
#define TF_R(r) { x0 += x1; x1 = rotl32(x1, r); x1 ^= x0; }
  TF_R(13) TF_R(15) TF_R(26) TF_R(6)
  x0 += k1;  x1 += ks2 + 1u;
  TF_R(17) TF_R(29) TF_R(16) TF_R(24)
  x0 += ks2; x1 += k0 + 2u;
  TF_R(13) TF_R(15) TF_R(26) TF_R(6)
  x0 += k0;  x1 += k1 + 3u;
  TF_R(17) TF_R(29) TF_R(16) TF_R(24)
  x0 += k1;  x1 += ks2 + 4u;
  TF_R(13) TF_R(15) TF_R(26) TF_R(6)
  x0 += ks2; x1 += k0 + 5u;
#undef TF_R
  o0 = x0; o1 = x1;
}

// 23-bit sort key of jax.random.uniform(key,(A,))[a]; score monotone in v,
// score ties <=> equal v (stable argsort -> smaller index ranks first).
__device__ static inline uint32_t anchor_vbits(uint32_t k0, uint32_t k1, int a) {
  uint32_t o0, o1;
#if PARTITIONABLE
  tf2x32(k0, k1, 0u, (uint32_t)a, o0, o1);
  return (o0 ^ o1) >> 9;
#else
  if (a < HALF_A) { tf2x32(k0, k1, (uint32_t)a, (uint32_t)(a + HALF_A), o0, o1); return o0 >> 9; }
  else            { tf2x32(k0, k1, (uint32_t)(a - HALF_A), (uint32_t)a, o0, o1); return o1 >> 9; }
#endif
}

// Box area, contraction off (bit-identical to XLA's plain fp32 ops).
__device__ static inline float area_of(float x0, float y0, float x1, float y1) {
#pragma clang fp contract(off)
  return (x1 - x0) * (y1 - y0);
}

// IoU with anchor area hoisted (bit-identical product order, XLA op-by-op).
__device__ static inline float iou_pre_a(float a0, float a1, float a2, float a3,
                                         float area_a,
                                         float g0, float g1, float g2, float g3) {
#pragma clang fp contract(off)
  float ltx = fmaxf(a0, g0), lty = fmaxf(a1, g1);
  float rbx = fminf(a2, g2), rby = fminf(a3, g3);
  float w = rbx - ltx; w = (w < 0.f) ? 0.f : w;
  float h = rby - lty; h = (h < 0.f) ? 0.f : h;
  float inter  = w * h;
  float area_g = (g2 - g0) * (g3 - g1);
  return inter / (area_a + area_g - inter + 1e-6f);
}

__device__ static inline void encode4(float4 an, float4 gg, float* tt) {
#pragma clang fp contract(off)
  float aw  = an.z - an.x,            ah  = an.w - an.y;
  float acx = (an.x + an.z) * 0.5f,   acy = (an.y + an.w) * 0.5f;
  float gw  = gg.z - gg.x,            gh  = gg.w - gg.y;
  float gcx = (gg.x + gg.z) * 0.5f,   gcy = (gg.y + gg.w) * 0.5f;
  tt[0] = (gcx - acx) / aw;
  tt[1] = (gcy - acy) / ah;
  tt[2] = logf(gw / aw);
  tt[3] = logf(gh / ah);
}

__device__ static inline int block_reduce_int(int v, int* sh) {
  int t = threadIdx.x;
  sh[t] = v; __syncthreads();
  for (int s = 128; s > 0; s >>= 1) { if (t < s) sh[t] += sh[t + s]; __syncthreads(); }
  int r = sh[0]; __syncthreads();
  return r;
}
__device__ static inline float block_reduce_float(float v, float* sh) {
  int t = threadIdx.x;
  sh[t] = v; __syncthreads();
  for (int s = 128; s > 0; s >>= 1) { if (t < s) sh[t] += sh[t + s]; __syncthreads(); }
  float r = sh[0]; __syncthreads();
  return r;
}

// Agent-scope (LLC-direct, L2-bypass) relaxed stores/loads: plain-store cost,
// no cache maintenance ops. Used for data a cross-XCD tail block must read.
__device__ static inline void st_agent_i32(int* p, int v) {
  __hip_atomic_store(p, v, __ATOMIC_RELAXED, __HIP_MEMORY_SCOPE_AGENT);
}
__device__ static inline void st_agent_u32(uint32_t* p, uint32_t v) {
  __hip_atomic_store(p, v, __ATOMIC_RELAXED, __HIP_MEMORY_SCOPE_AGENT);
}
__device__ static inline int ld_agent_i32(const int* p) {
  return __hip_atomic_load(p, __ATOMIC_RELAXED, __HIP_MEMORY_SCOPE_AGENT);
}
__device__ static inline uint32_t ld_agent_u32(const uint32_t* p) {
  return __hip_atomic_load(p, __ATOMIC_RELAXED, __HIP_MEMORY_SCOPE_AGENT);
}

// ---------------------------------------------------------------------------
// K1: IoU + labels + PRNG + hist + counts (all blocks, r9 body verbatim);
//     last-to-finish block runs force + cutoff serially.
// ---------------------------------------------------------------------------
__global__ __launch_bounds__(256) void iou_k(
    const float* __restrict__ anchors, const float* __restrict__ gtb,
    int* __restrict__ labels, int* __restrict__ mgt,
    uint32_t* __restrict__ vpos, uint32_t* __restrict__ vneg,
    int* __restrict__ ghist, int* __restrict__ counts,
    unsigned long long* __restrict__ gmax,
    int* __restrict__ cbR, int* __restrict__ targets,
    int* __restrict__ tickets, KeyParams kp) {
  __shared__ float2 gp01[2 * G_];               // (x0,y0), duplicated for mod-free idx
  __shared__ float2 gp23[2 * G_];               // (x1,y1), duplicated
  __shared__ unsigned long long slot2[2 * G_];  // per-(block,g residue) best pack
  __shared__ int red[256];
  __shared__ int sup[16];
  __shared__ int last;

  const int bid = blockIdx.x;
  const int t = threadIdx.x;
  const int b  = bid / (A_ / 256);
  const int xb = bid % (A_ / 256);
  const int a  = xb * 256 + t;                   // < A_ exactly
  const size_t idx = (size_t)b * A_ + a;

  // ========== phase 1: IoU + labels + PRNG + hist + counts ================
  {
    if (t < G_) {
      float4 gg = ((const float4*)gtb)[b * G_ + t];
      float2 p01; p01.x = gg.x; p01.y = gg.y;
      float2 p23; p23.x = gg.z; p23.y = gg.w;
      gp01[t] = p01; gp01[t + G_] = p01;
      gp23[t] = p23; gp23[t + G_] = p23;
    }
    slot2[t] = 0ull;                             // covers all 256 residues
    __syncthreads();

    float4 an = ((const float4*)anchors)[a];
    float area_a = area_of(an.x, an.y, an.z, an.w);
    const int t7 = t & (G_ - 1);
    const unsigned long long alow = (unsigned long long)(~(uint32_t)a);
    unsigned long long blp = 0ull;               // (iou_bits<<32 | g^127) running max
#pragma unroll 4
    for (int s = 0; s < G_; s++) {
      const int gi = t7 + s;                     // in [0, 254]; g = gi & 127
      float2 p01 = gp01[gi];
      float2 p23 = gp23[gi];
      float v = iou_pre_a(an.x, an.y, an.z, an.w, area_a,
                          p01.x, p01.y, p23.x, p23.y);
      unsigned long long hi = (unsigned long long)__float_as_uint(v) << 32;
      unsigned long long lp = hi | (unsigned)((gi & (G_ - 1)) ^ (G_ - 1));
      if (lp > blp) blp = lp;                    // (higher iou, then smaller g)
      atomicMax(&slot2[gi], hi | alow);          // fire-and-forget, lanes distinct
    }
    __syncthreads();
    if (t < G_) {
      unsigned long long p = slot2[t];
      unsigned long long q = slot2[t + G_];
      if (q > p) p = q;
      atomicMax(&gmax[b * G_ + t], p);           // once per (block, g)
    }

    float bv = __uint_as_float((uint32_t)(blp >> 32));
    int   bi = ((int)(blp & (unsigned long long)(G_ - 1))) ^ (G_ - 1);
    int lb = (bv < 0.3f) ? 0 : ((bv >= 0.7f) ? 1 : -1);
    uint32_t vp = anchor_vbits(kp.k[b][0], kp.k[b][1], a);
    uint32_t vn = anchor_vbits(kp.k[b][2], kp.k[b][3], a);
    st_agent_i32(&labels[idx], lb);    // LLC-direct: force tail atomicExch's
    st_agent_u32(&vpos[idx], vp);      // and its vpos/vneg reads must see them
    st_agent_u32(&vneg[idx], vn);
    mgt[idx] = bi;                     // only read after dispatch boundary (K2)
    if (lb == 1)      atomicAdd(&ghist[(b * 2 + 0) * NBUCK + (vp >> BSHIFT)], 1);
    else if (lb == 0) atomicAdd(&ghist[(b * 2 + 1) * NBUCK + (vn >> BSHIFT)], 1);
    // packed counts: pos | neg<<16 (block sums <= 256, safe)
    int packed = (lb == 1 ? 1 : 0) | ((lb == 0 ? 1 : 0) << 16);
    int rr = block_reduce_int(packed, red);
    if (t == 0) {
      atomicAdd(&counts[b * 2 + 0], rr & 0xFFFF);
      atomicAdd(&counts[b * 2 + 1], rr >> 16);
    }
  }

  // ---- ticket: __syncthreads drains vmcnt (sc1 stores acked at LLC) ------
  __syncthreads();
  if (t == 0) {
    int v = __hip_atomic_fetch_add(&tickets[0], 1, __ATOMIC_RELAXED,
                                   __HIP_MEMORY_SCOPE_AGENT);
    last = (v == NLAB - 1);
  }
  __syncthreads();
  if (!last) return;

  // ========== tail (one block): force best anchor per gt ==================
  for (int it = 0; it < (B_ * G_) / 256; ++it) {
    int tg = it * 256 + t;
    int fb = tg / G_;
    int fa = (int)(~(uint32_t)(gmax[tg] & 0xFFFFFFFFull));
    size_t fidx = (size_t)fb * A_ + fa;
    int old = atomicExch(&labels[fidx], 1);
    if (old != 1) {
      atomicAdd(&counts[fb * 2 + 0], 1);
      atomicAdd(&ghist[(fb * 2 + 0) * NBUCK + (ld_agent_u32(&vpos[fidx]) >> BSHIFT)], 1);
      if (old == 0) {
        atomicSub(&counts[fb * 2 + 1], 1);
        atomicSub(&ghist[(fb * 2 + 1) * NBUCK + (ld_agent_u32(&vneg[fidx]) >> BSHIFT)], 1);
      }
    }
  }
  __syncthreads();   // drain our atomics before plain ghist/counts reads

  // ========== tail: cutoff bucket + remainder (16 rows) ===================
  for (int row = 0; row < 2 * B_; ++row) {
    const int rb = row >> 1, rc = row & 1;
    int npos = counts[rb * 2 + 0], nneg = counts[rb * 2 + 1];
    int tp = npos < 128 ? npos : 128;
    int tn = 256 - tp; if (nneg < tn) tn = nneg;
    const int target = (rc == 0) ? tp : tn;
    const int* hist = ghist + (size_t)row * NBUCK;
    { int s = 0; const int base = t * 4;
      for (int i = 0; i < 4; i++) s += hist[base + i];
      red[t] = s; }
    __syncthreads();
    if (t < 16) { int ss = 0; for (int j = 0; j < 16; j++) ss += red[t * 16 + j]; sup[t] = ss; }
    __syncthreads();
    if (t == 0) {
      int cb = INT_MAX, R = 0;
      if (target > 0) {
        int cum = 0, si = 0;
        for (int i = 15; i >= 0; i--) { if (cum + sup[i] >= target) { si = i; break; } cum += sup[i]; }
        int sj = si * 16;
        for (int j = si * 16 + 15; j >= si * 16; j--) { if (cum + red[j] >= target) { sj = j; break; } cum += red[j]; }
        for (int k = sj * 4 + 3; k >= sj * 4; k--) {
          if (cum + hist[k] >= target) { cb = k; R = target - cum; break; }
          cum += hist[k];
        }
      }
      cbR[row * 2 + 0] = cb;
      cbR[row * 2 + 1] = R;
      targets[row] = target;
    }
    __syncthreads();
  }
}

// ---------------------------------------------------------------------------
// K2: merged cand + loss (all blocks, r11 phase3 verbatim); last-to-finish
//     block ranks cutoff-bucket candidates, adds their losses, writes out.
// ---------------------------------------------------------------------------
__global__ __launch_bounds__(256) void loss2_k(
    const float* __restrict__ anchors, const float* __restrict__ gtb,
    const float* __restrict__ cls, const float* __restrict__ boxp,
    const int* __restrict__ labels, const int* __restrict__ mgt,
    const uint32_t* __restrict__ vpos, const uint32_t* __restrict__ vneg,
    const int* __restrict__ cbR, const int* __restrict__ targets,
    int* __restrict__ ccnt, uint32_t* __restrict__ cvv, int* __restrict__ cii,
    float* __restrict__ bsums, int* __restrict__ tickets,
    float* __restrict__ out) {
  __shared__ float redf[256];
  __shared__ int last;

  const int bid = blockIdx.x;
  const int t = threadIdx.x;
  const int b  = bid / (A_ / 256);
  const int xb = bid % (A_ / 256);
  const int a  = xb * 256 + t;
  const size_t idx = (size_t)b * A_ + a;

  // ========== merged cand + loss ==========================================
  {
    float sb = 0.f, ss = 0.f;
    int lb = labels[idx];
    if (lb >= 0) {
      int c = (lb == 1) ? 0 : 1;
      int row = b * 2 + c;
      uint32_t v = (c == 0 ? vpos : vneg)[idx];
      int bucket = (int)(v >> BSHIFT);
      int cb = cbR[row * 2];
      if (bucket == cb) {
        // deferred: rank unknown until all candidates appended
        int p = atomicAdd(&ccnt[row], 1);
        if (p < CAP) {
          st_agent_u32(&cvv[row * CAP + p], v);   // tail reads cross-XCD
          st_agent_i32(&cii[row * CAP + p], a);
        }
      } else if (bucket > cb) {                  // sure-kept (cb==INT_MAX -> never)
        int kk = a % K_; int hw = a / K_; int hh = hw / W_; int wx = hw % W_;
        float x  = cls[(((size_t)b * K_ + kk) * H_ + hh) * W_ + wx];
        float sp = fmaxf(x, 0.f) + log1pf(expf(-fabsf(x)));   // logaddexp(x,0)
        sb = (lb == 1) ? (sp - x) : sp;
        if (lb == 1) {
          float4 an = ((const float4*)anchors)[a];
          int    mg = mgt[idx];
          float4 gg = ((const float4*)gtb)[b * G_ + mg];
          float tt[4]; encode4(an, gg, tt);
          for (int cc2 = 0; cc2 < 4; cc2++) {
            float p = boxp[(((size_t)b * (4 * K_) + (4 * kk + cc2)) * H_ + hh) * W_ + wx];
            float d = p - tt[cc2];
            float ad = fabsf(d);
            ss += (ad < 1.f) ? (0.5f * d * d) : (ad - 0.5f);
          }
        }
      }
    }
    float sbT = block_reduce_float(sb, redf);
    float ssT = block_reduce_float(ss, redf);
    if (t == 0) {
      if (sbT != 0.f) atomicAdd(&bsums[b * 2 + 0], sbT);
      if (ssT != 0.f) atomicAdd(&bsums[b * 2 + 1], ssT);
    }
  }

  // ---- ticket ------------------------------------------------------------
  __syncthreads();
  if (t == 0) {
    int v = __hip_atomic_fetch_add(&tickets[1], 1, __ATOMIC_RELAXED,
                                   __HIP_MEMORY_SCOPE_AGENT);
    last = (v == NLAB - 1);
  }
  __syncthreads();
  if (!last) return;

  // ========== tail: candidate ranking + losses + final ====================
  for (int row = 0; row < 2 * B_; ++row) {
    int c2 = ld_agent_i32(&ccnt[row]); if (c2 > CAP) c2 = CAP;
    int R = cbR[row * 2 + 1];
    const int rb = row >> 1;
    const bool pos = ((row & 1) == 0);
    float sbl = 0.f, ssl = 0.f;
    for (int j = t; j < c2; j += 256) {
      uint32_t v = ld_agent_u32(&cvv[row * CAP + j]);
      int a2 = ld_agent_i32(&cii[row * CAP + j]);
      int r = 0;
      for (int k2 = 0; k2 < c2; k2++) {
        uint32_t vk = ld_agent_u32(&cvv[row * CAP + k2]);
        int ik = ld_agent_i32(&cii[row * CAP + k2]);
        if (vk > v || (vk == v && ik < a2)) r++;
      }
      if (r < R) {                                // kept: stable-rank subsample
        int kk = a2 % K_; int hw = a2 / K_; int hh = hw / W_; int wx = hw % W_;
        float x = cls[(((size_t)rb * K_ + kk) * H_ + hh) * W_ + wx];
        float sp = fmaxf(x, 0.f) + log1pf(expf(-fabsf(x)));
        sbl += pos ? (sp - x) : sp;
        if (pos) {
          float4 an = ((const float4*)anchors)[a2];
          int mg = mgt[(size_t)rb * A_ + a2];
          float4 gg = ((const float4*)gtb)[rb * G_ + mg];
          float tt[4]; encode4(an, gg, tt);
          for (int cc2 = 0; cc2 < 4; cc2++) {
            float p = boxp[(((size_t)rb * (4 * K_) + (4 * kk + cc2)) * H_ + hh) * W_ + wx];
            float d = p - tt[cc2];
            float ad = fabsf(d);
            ssl += (ad < 1.f) ? (0.5f * d * d) : (ad - 0.5f);
          }
        }
      }
    }
    if (sbl != 0.f) atomicAdd(&bsums[rb * 2 + 0], sbl);
    if (ssl != 0.f) atomicAdd(&bsums[rb * 2 + 1], ssl);
  }
  __syncthreads();   // drain our bsums atomics before plain reads
  if (t == 0) {
    float cl = 0.f, bl = 0.f;
    for (int bb = 0; bb < B_; bb++) {
      int tp = targets[bb * 2 + 0], tn = targets[bb * 2 + 1];
      cl += bsums[bb * 2 + 0] / fmaxf((float)(tp + tn), 1.f);
      bl += bsums[bb * 2 + 1] / fmaxf(4.f * (float)tp, 1.f);
    }
    cl *= 0.125f; bl *= 0.125f;
    out[0] = cl; out[1] = bl; out[2] = cl + bl;
  }
}

static void compute_keys(KeyParams& kp) {
  const uint32_t r0 = 0u, r1 = 42u;        // jax.random.key(42) -> (hi, lo)
#if PARTITIONABLE
  for (int b = 0; b < B_; b++) {
    uint32_t kb0, kb1;
    tf2x32(r0, r1, 0u, (uint32_t)b, kb0, kb1);        // split(root, 8)[b]
    uint32_t a0, a1, c0, c1;
    tf2x32(kb0, kb1, 0u, 0u, a0, a1);                 // split(key)[0] = k1
    tf2x32(kb0, kb1, 0u, 1u, c0, c1);                 // split(key)[1] = k2
    kp.k[b][0] = a0; kp.k[b][1] = a1; kp.k[b][2] = c0; kp.k[b][3] = c1;
  }
#else
  uint32_t o0[8], o1[8], flat[16];
  for (int i = 0; i < 8; i++) tf2x32(r0, r1, (uint32_t)i, (uint32_t)(8 + i), o0[i], o1[i]);
  for (int i = 0; i < 8; i++) { flat[i] = o0[i]; flat[8 + i] = o1[i]; }
  for (int b = 0; b < B_; b++) {
    uint32_t kb0 = flat[2 * b], kb1 = flat[2 * b + 1];
    uint32_t a0, b0, a1, b1;
    tf2x32(kb0, kb1, 0u, 2u, a0, b0);
    tf2x32(kb0, kb1, 1u, 3u, a1, b1);
    kp.k[b][0] = a0; kp.k[b][1] = a1; kp.k[b][2] = b0; kp.k[b][3] = b1;
  }
#endif
}

extern "C" void kernel_launch(void* const* d_in, const int* in_sizes, int n_in,
                              void* d_out, int out_size, void* d_ws, size_t ws_size,
                              hipStream_t stream) {
  const float* cls     = (const float*)d_in[0];   // [B,K,H,W]
  const float* boxp    = (const float*)d_in[1];   // [B,4K,H,W]
  const float* anchors = (const float*)d_in[2];   // [A,4]
  const float* gtb     = (const float*)d_in[3];   // [B,G,4]
  float* out = (float*)d_out;

  uint8_t* w = (uint8_t*)d_ws;
  // zeroed region [0, 74240): gmax + ghist + counts + ccnt + bsums + tickets
  // (small arrays padded to 128B lines so atomic-only lines never share with
  //  plain-read lines in an unflushed L2)
  unsigned long long* gmax = (unsigned long long*)w;    // B*G u64 (8 KB)
  int*      ghist   = (int*)(w + 8192);                 // 16*NBUCK ints (64 KB)
  int*      counts  = (int*)(w + 73728);                // 16 ints (pad 128)
  int*      ccnt    = (int*)(w + 73856);                // 16 ints (pad 128)
  float*    bsums   = (float*)(w + 73984);              // 16 floats (pad 128)
  int*      tickets = (int*)(w + 74112);                // 2 ints (pad 128)
  // non-zeroed region
  int*      labels  = (int*)(w + 74240);                // B*A
  int*      mgt     = labels + (size_t)B_ * A_;         // B*A
  uint32_t* vpos    = (uint32_t*)(mgt + (size_t)B_ * A_);  // B*A
  uint32_t* vneg    = vpos + (size_t)B_ * A_;           // B*A
  int*      cbR     = (int*)(vneg + (size_t)B_ * A_);   // 32
  int*      targets = cbR + 32;                         // 16
  uint32_t* cvv     = (uint32_t*)(targets + 16);        // 16*CAP
  int*      cii     = (int*)(cvv + 16 * CAP);           // 16*CAP

  KeyParams kp;
  compute_keys(kp);

  (void)hipMemsetAsync(w, 0, 74240, stream);
  iou_k<<<NLAB, 256, 0, stream>>>(anchors, gtb, labels, mgt, vpos, vneg,
                                  ghist, counts, gmax, cbR, targets, tickets, kp);
  loss2_k<<<NLAB, 256, 0, stream>>>(anchors, gtb, cls, boxp, labels, mgt,
                                    vpos, vneg, cbR, targets, ccnt, cvv, cii,
                                    bsums, tickets, out);
}

// Round 6
// 144.786 us; speedup vs baseline: 16.0239x; 1.4949x over previous
//
#include <hip/hip_runtime.h>
#include <stdint.h>
#include <limits.h>

// ---------------------------------------------------------------------------
// RPN loss, bit-exact replication of the JAX reference (incl. threefry PRNG).
// Round 14: r13's fence-free ticket fusion PASSED (absmax 0.0) but the
// single-block serial tails were latency-hell (loss2_k 86us @ VALUBusy 1%,
// occupancy 7.6% -- one block doing O(c^2) agent-loads serially).
// Fix, keeping the proven visibility mechanism bit-for-bit:
//  - PER-IMAGE tickets (8 x 144 arrivals): last block of image b runs image
//    b's tail -> tails 8-way parallel, overlapped with other images' bodies.
//  - K2 tail stages the row's ~40 candidates into LDS once, ranks from LDS
//    (was: O(c^2) serialized LLC round trips).
//  - cbR/targets written sc1 (byte-granular at LLC; 8 writers, no cross-XCD
//    dirty-line hazard).
//  - final combine gated by an 8-arrival second-level ticket.
// ---------------------------------------------------------------------------
#define PARTITIONABLE 1

#define B_ 8
#define K_ 9
#define H_ 64
#define W_ 64
#define G_ 128
#define A_ 36864            // K*H*W
#define HALF_A 18432
#define NBUCK 1024          // buckets over 23-bit v (v>>13)
#define BSHIFT 13
#define CAP 1024            // cutoff-bucket candidate capacity (expected ~40)
#define NLAB  1152          // (A_/256) * B_  -- one block per 256 anchors
#define NPB   144           // blocks per image = A_/256

struct KeyParams { uint32_t k[B_][4]; };   // per image: k1.(0,1), k2.(0,1)

__host__ __device__ static inline uint32_t rotl32(uint32_t x, int r) {
  return (x << r) | (x >> (32 - r));
}

// JAX threefry2x32: 20 rounds, key injections every 4 rounds.
__host__ __device__ static inline void tf2x32(uint32_t k0, uint32_t k1,
                                              uint32_t x0, uint32_t x1,
                                              uint32_t& o0, uint32_t& o1) {
  uint32_t ks2 = k0 ^ k1 ^ 0x1BD11BDAu;
  x0 += k0; x1 += k1;
#define TF_R(r) { x0 += x1; x1 = rotl32(x1, r); x1 ^= x0; }
  TF_R(13) TF_R(15) TF_R(26) TF_R(6)
  x0 += k1;  x1 += ks2 + 1u;
  TF_R(17) TF_R(29) TF_R(16) TF_R(24)
  x0 += ks2; x1 += k0 + 2u;
  TF_R(13) TF_R(15) TF_R(26) TF_R(6)
  x0 += k0;  x1 += k1 + 3u;
  TF_R(17) TF_R(29) TF_R(16) TF_R(24)
  x0 += k1;  x1 += ks2 + 4u;
  TF_R(13) TF_R(15) TF_R(26) TF_R(6)
  x0 += ks2; x1 += k0 + 5u;
#undef TF_R
  o0 = x0; o1 = x1;
}

// 23-bit sort key of jax.random.uniform(key,(A,))[a]; score monotone in v,
// score ties <=> equal v (stable argsort -> smaller index ranks first).
__device__ static inline uint32_t anchor_vbits(uint32_t k0, uint32_t k1, int a) {
  uint32_t o0, o1;
#if PARTITIONABLE
  tf2x32(k0, k1, 0u, (uint32_t)a, o0, o1);
  return (o0 ^ o1) >> 9;
#else
  if (a < HALF_A) { tf2x32(k0, k1, (uint32_t)a, (uint32_t)(a + HALF_A), o0, o1); return o0 >> 9; }
  else            { tf2x32(k0, k1, (uint32_t)(a - HALF_A), (uint32_t)a, o0, o1); return o1 >> 9; }
#endif
}

// Box area, contraction off (bit-identical to XLA's plain fp32 ops).
__device__ static inline float area_of(float x0, float y0, float x1, float y1) {
#pragma clang fp contract(off)
  return (x1 - x0) * (y1 - y0);
}

// IoU with anchor area hoisted (bit-identical product order, XLA op-by-op).
__device__ static inline float iou_pre_a(float a0, float a1, float a2, float a3,
                                         float area_a,
                                         float g0, float g1, float g2, float g3) {
#pragma clang fp contract(off)
  float ltx = fmaxf(a0, g0), lty = fmaxf(a1, g1);
  float rbx = fminf(a2, g2), rby = fminf(a3, g3);
  float w = rbx - ltx; w = (w < 0.f) ? 0.f : w;
  float h = rby - lty; h = (h < 0.f) ? 0.f : h;
  float inter  = w * h;
  float area_g = (g2 - g0) * (g3 - g1);
  return inter / (area_a + area_g - inter + 1e-6f);
}

__device__ static inline void encode4(float4 an, float4 gg, float* tt) {
#pragma clang fp contract(off)
  float aw  = an.z - an.x,            ah  = an.w - an.y;
  float acx = (an.x + an.z) * 0.5f,   acy = (an.y + an.w) * 0.5f;
  float gw  = gg.z - gg.x,            gh  = gg.w - gg.y;
  float gcx = (gg.x + gg.z) * 0.5f,   gcy = (gg.y + gg.w) * 0.5f;
  tt[0] = (gcx - acx) / aw;
  tt[1] = (gcy - acy) / ah;
  tt[2] = logf(gw / aw);
  tt[3] = logf(gh / ah);
}

__device__ static inline int block_reduce_int(int v, int* sh) {
  int t = threadIdx.x;
  sh[t] = v; __syncthreads();
  for (int s = 128; s > 0; s >>= 1) { if (t < s) sh[t] += sh[t + s]; __syncthreads(); }
  int r = sh[0]; __syncthreads();
  return r;
}
__device__ static inline float block_reduce_float(float v, float* sh) {
  int t = threadIdx.x;
  sh[t] = v; __syncthreads();
  for (int s = 128; s > 0; s >>= 1) { if (t < s) sh[t] += sh[t + s]; __syncthreads(); }
  float r = sh[0]; __syncthreads();
  return r;
}

// Agent-scope (LLC-direct, L2-bypass) relaxed stores/loads: plain-store cost,
// no cache maintenance ops. Used for data a cross-XCD tail block must read.
__device__ static inline void st_agent_i32(int* p, int v) {
  __hip_atomic_store(p, v, __ATOMIC_RELAXED, __HIP_MEMORY_SCOPE_AGENT);
}
__device__ static inline void st_agent_u32(uint32_t* p, uint32_t v) {
  __hip_atomic_store(p, v, __ATOMIC_RELAXED, __HIP_MEMORY_SCOPE_AGENT);
}
__device__ static inline int ld_agent_i32(const int* p) {
  return __hip_atomic_load(p, __ATOMIC_RELAXED, __HIP_MEMORY_SCOPE_AGENT);
}
__device__ static inline uint32_t ld_agent_u32(const uint32_t* p) {
  return __hip_atomic_load(p, __ATOMIC_RELAXED, __HIP_MEMORY_SCOPE_AGENT);
}
__device__ static inline unsigned long long ld_agent_u64(const unsigned long long* p) {
  return __hip_atomic_load(p, __ATOMIC_RELAXED, __HIP_MEMORY_SCOPE_AGENT);
}
__device__ static inline float ld_agent_f32(const float* p) {
  return __hip_atomic_load(p, __ATOMIC_RELAXED, __HIP_MEMORY_SCOPE_AGENT);
}

// ---------------------------------------------------------------------------
// K1: IoU + labels + PRNG + hist + counts (all blocks, r9 body verbatim);
//     per-image last block runs that image's force + cutoff (parallel lanes).
// ---------------------------------------------------------------------------
__global__ __launch_bounds__(256) void iou_k(
    const float* __restrict__ anchors, const float* __restrict__ gtb,
    int* __restrict__ labels, int* __restrict__ mgt,
    uint32_t* __restrict__ vpos, uint32_t* __restrict__ vneg,
    int* __restrict__ ghist, int* __restrict__ counts,
    unsigned long long* __restrict__ gmax,
    int* __restrict__ cbR, int* __restrict__ targets,
    int* __restrict__ tickets, KeyParams kp) {
  __shared__ float2 gp01[2 * G_];               // (x0,y0), duplicated for mod-free idx
  __shared__ float2 gp23[2 * G_];               // (x1,y1), duplicated
  __shared__ unsigned long long slot2[2 * G_];  // per-(block,g residue) best pack
  __shared__ int red[256];
  __shared__ int sup[16];
  __shared__ int last;

  const int bid = blockIdx.x;
  const int t = threadIdx.x;
  const int b  = bid / NPB;
  const int xb = bid % NPB;
  const int a  = xb * 256 + t;                   // < A_ exactly
  const size_t idx = (size_t)b * A_ + a;

  // ========== phase 1: IoU + labels + PRNG + hist + counts ================
  {
    if (t < G_) {
      float4 gg = ((const float4*)gtb)[b * G_ + t];
      float2 p01; p01.x = gg.x; p01.y = gg.y;
      float2 p23; p23.x = gg.z; p23.y = gg.w;
      gp01[t] = p01; gp01[t + G_] = p01;
      gp23[t] = p23; gp23[t + G_] = p23;
    }
    slot2[t] = 0ull;                             // covers all 256 residues
    __syncthreads();

    float4 an = ((const float4*)anchors)[a];
    float area_a = area_of(an.x, an.y, an.z, an.w);
    const int t7 = t & (G_ - 1);
    const unsigned long long alow = (unsigned long long)(~(uint32_t)a);
    unsigned long long blp = 0ull;               // (iou_bits<<32 | g^127) running max
#pragma unroll 4
    for (int s = 0; s < G_; s++) {
      const int gi = t7 + s;                     // in [0, 254]; g = gi & 127
      float2 p01 = gp01[gi];
      float2 p23 = gp23[gi];
      float v = iou_pre_a(an.x, an.y, an.z, an.w, area_a,
                          p01.x, p01.y, p23.x, p23.y);
      unsigned long long hi = (unsigned long long)__float_as_uint(v) << 32;
      unsigned long long lp = hi | (unsigned)((gi & (G_ - 1)) ^ (G_ - 1));
      if (lp > blp) blp = lp;                    // (higher iou, then smaller g)
      atomicMax(&slot2[gi], hi | alow);          // fire-and-forget, lanes distinct
    }
    __syncthreads();
    if (t < G_) {
      unsigned long long p = slot2[t];
      unsigned long long q = slot2[t + G_];
      if (q > p) p = q;
      atomicMax(&gmax[b * G_ + t], p);           // once per (block, g)
    }

    float bv = __uint_as_float((uint32_t)(blp >> 32));
    int   bi = ((int)(blp & (unsigned long long)(G_ - 1))) ^ (G_ - 1);
    int lb = (bv < 0.3f) ? 0 : ((bv >= 0.7f) ? 1 : -1);
    uint32_t vp = anchor_vbits(kp.k[b][0], kp.k[b][1], a);
    uint32_t vn = anchor_vbits(kp.k[b][2], kp.k[b][3], a);
    st_agent_i32(&labels[idx], lb);    // LLC-direct: in-kernel force tail RMWs
    st_agent_u32(&vpos[idx], vp);      // and reads these cross-XCD
    st_agent_u32(&vneg[idx], vn);
    mgt[idx] = bi;                     // only read after dispatch boundary (K2)
    if (lb == 1)      atomicAdd(&ghist[(b * 2 + 0) * NBUCK + (vp >> BSHIFT)], 1);
    else if (lb == 0) atomicAdd(&ghist[(b * 2 + 1) * NBUCK + (vn >> BSHIFT)], 1);
    // packed counts: pos | neg<<16 (block sums <= 256, safe)
    int packed = (lb == 1 ? 1 : 0) | ((lb == 0 ? 1 : 0) << 16);
    int rr = block_reduce_int(packed, red);
    if (t == 0) {
      atomicAdd(&counts[b * 2 + 0], rr & 0xFFFF);
      atomicAdd(&counts[b * 2 + 1], rr >> 16);
    }
  }

  // ---- per-image ticket: syncthreads drains vmcnt (stores acked at LLC) --
  __syncthreads();
  if (t == 0) {
    int v = __hip_atomic_fetch_add(&tickets[b], 1, __ATOMIC_RELAXED,
                                   __HIP_MEMORY_SCOPE_AGENT);
    last = (v == NPB - 1);
  }
  __syncthreads();
  if (!last) return;

  // ========== tail (last image-b block): force best anchor per gt =========
  if (t < G_) {
    unsigned long long gm = ld_agent_u64(&gmax[b * G_ + t]);
    int fa = (int)(~(uint32_t)(gm & 0xFFFFFFFFull));
    size_t fidx = (size_t)b * A_ + fa;
    int old = atomicExch(&labels[fidx], 1);
    if (old != 1) {
      atomicAdd(&counts[b * 2 + 0], 1);
      atomicAdd(&ghist[(b * 2 + 0) * NBUCK + (ld_agent_u32(&vpos[fidx]) >> BSHIFT)], 1);
      if (old == 0) {
        atomicSub(&counts[b * 2 + 1], 1);
        atomicSub(&ghist[(b * 2 + 1) * NBUCK + (ld_agent_u32(&vneg[fidx]) >> BSHIFT)], 1);
      }
    }
  }
  __syncthreads();   // drain force atomics before counts/ghist reads

  // ========== tail: cutoff bucket + remainder (2 rows of this image) ======
  int npos = ld_agent_i32(&counts[b * 2 + 0]);
  int nneg = ld_agent_i32(&counts[b * 2 + 1]);
  int tp = npos < 128 ? npos : 128;
  int tn = 256 - tp; if (nneg < tn) tn = nneg;
  for (int c = 0; c < 2; ++c) {
    const int row = b * 2 + c;
    const int target = (c == 0) ? tp : tn;
    const int* hist = ghist + (size_t)row * NBUCK;
    { int s = 0; const int base = t * 4;
      for (int i = 0; i < 4; i++) s += ld_agent_i32(&hist[base + i]);
      red[t] = s; }
    __syncthreads();
    if (t < 16) { int ss = 0; for (int j = 0; j < 16; j++) ss += red[t * 16 + j]; sup[t] = ss; }
    __syncthreads();
    if (t == 0) {
      int cb = INT_MAX, R = 0;
      if (target > 0) {
        int cum = 0, si = 0;
        for (int i = 15; i >= 0; i--) { if (cum + sup[i] >= target) { si = i; break; } cum += sup[i]; }
        int sj = si * 16;
        for (int j = si * 16 + 15; j >= si * 16; j--) { if (cum + red[j] >= target) { sj = j; break; } cum += red[j]; }
        for (int k = sj * 4 + 3; k >= sj * 4; k--) {
          int hv = ld_agent_i32(&hist[k]);
          if (cum + hv >= target) { cb = k; R = target - cum; break; }
          cum += hv;
        }
      }
      st_agent_i32(&cbR[row * 2 + 0], cb);     // 8 writer blocks: LLC-direct,
      st_agent_i32(&cbR[row * 2 + 1], R);      // byte-granular, no dirty-line
      st_agent_i32(&targets[row], target);     // clobber across XCDs
    }
    __syncthreads();
  }
}

// ---------------------------------------------------------------------------
// K2: merged cand + loss (all blocks); per-image last block ranks that
//     image's cutoff-bucket candidates from LDS; 8th tail writes out.
// ---------------------------------------------------------------------------
__global__ __launch_bounds__(256) void loss2_k(
    const float* __restrict__ anchors, const float* __restrict__ gtb,
    const float* __restrict__ cls, const float* __restrict__ boxp,
    const int* __restrict__ labels, const int* __restrict__ mgt,
    const uint32_t* __restrict__ vpos, const uint32_t* __restrict__ vneg,
    const int* __restrict__ cbR, const int* __restrict__ targets,
    int* __restrict__ ccnt, uint32_t* __restrict__ cvv, int* __restrict__ cii,
    float* __restrict__ bsums, int* __restrict__ tickets,
    float* __restrict__ out) {
  __shared__ float redf[256];
  __shared__ uint32_t scv[CAP];
  __shared__ int sci[CAP];
  __shared__ int last;

  const int bid = blockIdx.x;
  const int t = threadIdx.x;
  const int b  = bid / NPB;
  const int xb = bid % NPB;
  const int a  = xb * 256 + t;
  const size_t idx = (size_t)b * A_ + a;

  // ========== merged cand + loss ==========================================
  {
    float sb = 0.f, ss = 0.f;
    int lb = labels[idx];
    if (lb >= 0) {
      int c = (lb == 1) ? 0 : 1;
      int row = b * 2 + c;
      uint32_t v = (c == 0 ? vpos : vneg)[idx];
      int bucket = (int)(v >> BSHIFT);
      int cb = cbR[row * 2];
      if (bucket == cb) {
        // deferred: rank unknown until all candidates appended
        int p = atomicAdd(&ccnt[row], 1);
        if (p < CAP) {
          st_agent_u32(&cvv[row * CAP + p], v);   // tail reads cross-XCD
          st_agent_i32(&cii[row * CAP + p], a);
        }
      } else if (bucket > cb) {                  // sure-kept (cb==INT_MAX -> never)
        int kk = a % K_; int hw = a / K_; int hh = hw / W_; int wx = hw % W_;
        float x  = cls[(((size_t)b * K_ + kk) * H_ + hh) * W_ + wx];
        float sp = fmaxf(x, 0.f) + log1pf(expf(-fabsf(x)));   // logaddexp(x,0)
        sb = (lb == 1) ? (sp - x) : sp;
        if (lb == 1) {
          float4 an = ((const float4*)anchors)[a];
          int    mg = mgt[idx];
          float4 gg = ((const float4*)gtb)[b * G_ + mg];
          float tt[4]; encode4(an, gg, tt);
          for (int cc2 = 0; cc2 < 4; cc2++) {
            float p = boxp[(((size_t)b * (4 * K_) + (4 * kk + cc2)) * H_ + hh) * W_ + wx];
            float d = p - tt[cc2];
            float ad = fabsf(d);
            ss += (ad < 1.f) ? (0.5f * d * d) : (ad - 0.5f);
          }
        }
      }
    }
    float sbT = block_reduce_float(sb, redf);
    float ssT = block_reduce_float(ss, redf);
    if (t == 0) {
      if (sbT != 0.f) atomicAdd(&bsums[b * 2 + 0], sbT);
      if (ssT != 0.f) atomicAdd(&bsums[b * 2 + 1], ssT);
    }
  }

  // ---- per-image ticket --------------------------------------------------
  __syncthreads();
  if (t == 0) {
    int v = __hip_atomic_fetch_add(&tickets[8 + b], 1, __ATOMIC_RELAXED,
                                   __HIP_MEMORY_SCOPE_AGENT);
    last = (v == NPB - 1);
  }
  __syncthreads();
  if (!last) return;

  // ========== tail (last image-b block): rank this image's 2 rows =========
  for (int c = 0; c < 2; ++c) {
    const int row = b * 2 + c;
    int c2 = ld_agent_i32(&ccnt[row]); if (c2 > CAP) c2 = CAP;
    const int R = cbR[row * 2 + 1];
    for (int j = t; j < c2; j += 256) {
      scv[j] = ld_agent_u32(&cvv[row * CAP + j]);
      sci[j] = ld_agent_i32(&cii[row * CAP + j]);
    }
    __syncthreads();
    const bool pos = (c == 0);
    float sbl = 0.f, ssl = 0.f;
    for (int j = t; j < c2; j += 256) {
      uint32_t v = scv[j]; int a2 = sci[j];
      int r = 0;
      for (int k2 = 0; k2 < c2; k2++) {
        uint32_t vk = scv[k2]; int ik = sci[k2];
        if (vk > v || (vk == v && ik < a2)) r++;
      }
      if (r < R) {                                // kept: stable-rank subsample
        int kk = a2 % K_; int hw = a2 / K_; int hh = hw / W_; int wx = hw % W_;
        float x = cls[(((size_t)b * K_ + kk) * H_ + hh) * W_ + wx];
        float sp = fmaxf(x, 0.f) + log1pf(expf(-fabsf(x)));
        sbl += pos ? (sp - x) : sp;
        if (pos) {
          float4 an = ((const float4*)anchors)[a2];
          int mg = mgt[(size_t)b * A_ + a2];
          float4 gg = ((const float4*)gtb)[b * G_ + mg];
          float tt[4]; encode4(an, gg, tt);
          for (int cc2 = 0; cc2 < 4; cc2++) {
            float p = boxp[(((size_t)b * (4 * K_) + (4 * kk + cc2)) * H_ + hh) * W_ + wx];
            float d = p - tt[cc2];
            float ad = fabsf(d);
            ssl += (ad < 1.f) ? (0.5f * d * d) : (ad - 0.5f);
          }
        }
      }
    }
    float sbT = block_reduce_float(sbl, redf);
    float ssT = block_reduce_float(ssl, redf);
    if (t == 0) {
      if (sbT != 0.f) atomicAdd(&bsums[b * 2 + 0], sbT);
      if (ssT != 0.f) atomicAdd(&bsums[b * 2 + 1], ssT);
    }
    __syncthreads();
  }

  // ---- final ticket: 8 arrivals, one per image tail ----------------------
  __syncthreads();   // drain bsums atomics
  if (t == 0) {
    int v = __hip_atomic_fetch_add(&tickets[16], 1, __ATOMIC_RELAXED,
                                   __HIP_MEMORY_SCOPE_AGENT);
    last = (v == B_ - 1);
  }
  __syncthreads();
  if (!last) return;

  if (t == 0) {
    float cl = 0.f, bl = 0.f;
    for (int bb = 0; bb < B_; bb++) {
      int tpv = ld_agent_i32(&targets[bb * 2 + 0]);
      int tnv = ld_agent_i32(&targets[bb * 2 + 1]);
      float s0 = ld_agent_f32(&bsums[bb * 2 + 0]);
      float s1 = ld_agent_f32(&bsums[bb * 2 + 1]);
      cl += s0 / fmaxf((float)(tpv + tnv), 1.f);
      bl += s1 / fmaxf(4.f * (float)tpv, 1.f);
    }
    cl *= 0.125f; bl *= 0.125f;
    out[0] = cl; out[1] = bl; out[2] = cl + bl;
  }
}

static void compute_keys(KeyParams& kp) {
  const uint32_t r0 = 0u, r1 = 42u;        // jax.random.key(42) -> (hi, lo)
#if PARTITIONABLE
  for (int b = 0; b < B_; b++) {
    uint32_t kb0, kb1;
    tf2x32(r0, r1, 0u, (uint32_t)b, kb0, kb1);        // split(root, 8)[b]
    uint32_t a0, a1, c0, c1;
    tf2x32(kb0, kb1, 0u, 0u, a0, a1);                 // split(key)[0] = k1
    tf2x32(kb0, kb1, 0u, 1u, c0, c1);                 // split(key)[1] = k2
    kp.k[b][0] = a0; kp.k[b][1] = a1; kp.k[b][2] = c0; kp.k[b][3] = c1;
  }
#else
  uint32_t o0[8], o1[8], flat[16];
  for (int i = 0; i < 8; i++) tf2x32(r0, r1, (uint32_t)i, (uint32_t)(8 + i), o0[i], o1[i]);
  for (int i = 0; i < 8; i++) { flat[i] = o0[i]; flat[8 + i] = o1[i]; }
  for (int b = 0; b < B_; b++) {
    uint32_t kb0 = flat[2 * b], kb1 = flat[2 * b + 1];
    uint32_t a0, b0, a1, b1;
    tf2x32(kb0, kb1, 0u, 2u, a0, b0);
    tf2x32(kb0, kb1, 1u, 3u, a1, b1);
    kp.k[b][0] = a0; kp.k[b][1] = a1; kp.k[b][2] = b0; kp.k[b][3] = b1;
  }
#endif
}

extern "C" void kernel_launch(void* const* d_in, const int* in_sizes, int n_in,
                              void* d_out, int out_size, void* d_ws, size_t ws_size,
                              hipStream_t stream) {
  const float* cls     = (const float*)d_in[0];   // [B,K,H,W]
  const float* boxp    = (const float*)d_in[1];   // [B,4K,H,W]
  const float* anchors = (const float*)d_in[2];   // [A,4]
  const float* gtb     = (const float*)d_in[3];   // [B,G,4]
  float* out = (float*)d_out;

  uint8_t* w = (uint8_t*)d_ws;
  // zeroed region [0, 74240): gmax + ghist + counts + ccnt + bsums + tickets
  unsigned long long* gmax = (unsigned long long*)w;    // B*G u64 (8 KB)
  int*      ghist   = (int*)(w + 8192);                 // 16*NBUCK ints (64 KB)
  int*      counts  = (int*)(w + 73728);                // 16 ints (pad 128)
  int*      ccnt    = (int*)(w + 73856);                // 16 ints (pad 128)
  float*    bsums   = (float*)(w + 73984);              // 16 floats (pad 128)
  int*      tickets = (int*)(w + 74112);                // 32 ints (pad 128):
                                                        // [0..7] K1, [8..15] K2, [16] final
  // non-zeroed region
  int*      labels  = (int*)(w + 74240);                // B*A
  int*      mgt     = labels + (size_t)B_ * A_;         // B*A
  uint32_t* vpos    = (uint32_t*)(mgt + (size_t)B_ * A_);  // B*A
  uint32_t* vneg    = vpos + (size_t)B_ * A_;           // B*A
  int*      cbR     = (int*)(vneg + (size_t)B_ * A_);   // 32
  int*      targets = cbR + 32;                         // 16
  uint32_t* cvv     = (uint32_t*)(targets + 16);        // 16*CAP
  int*      cii     = (int*)(cvv + 16 * CAP);           // 16*CAP

  KeyParams kp;
  compute_keys(kp);

  (void)hipMemsetAsync(w, 0, 74240, stream);
  iou_k<<<NLAB, 256, 0, stream>>>(anchors, gtb, labels, mgt, vpos, vneg,
                                  ghist, counts, gmax, cbR, targets, tickets, kp);
  loss2_k<<<NLAB, 256, 0, stream>>>(anchors, gtb, cls, boxp, labels, mgt,
                                    vpos, vneg, cbR, targets, ccnt, cvv, cii,
                                    bsums, tickets, out);
}